// Round 1
// baseline (1714.260 us; speedup 1.0000x reference)
//
#include <hip/hip_runtime.h>
#include <math.h>

// ---------------------------------------------------------------------------
// AttentionalSpikingSSMLayer  (B=8, T=16, S=256, D=512, DS=64, H=4, dh=16)
// N = B*S = 2048 flattened tokens; attention mixes the whole batch (as ref).
// All compute fp32 (no fp32 MFMA on CDNA4; spikes are Heaviside -> need fp32
// accuracy to avoid threshold flips).
// ---------------------------------------------------------------------------

#define NTOK   2048          // B*S
#define DS     64
#define DMODEL 512
#define NH     4
#define DH     16
#define TSTEPS 16
#define NSPLIT 32            // key splits for flash partials
#define KEYS_PER_SPLIT (NTOK / NSPLIT)   // 64

#define MEMDECAY ((float)0.6065306597126334)
#define SCALE    0.25f       // 1/sqrt(dh)

// workspace layout (float offsets)
#define OFF_KV   ((size_t)0)                      // 16*2048*128 = 4,194,304
#define OFF_PACC ((size_t)4194304)                // 4*32*2048*16 = 4,194,304
#define OFF_OV   ((size_t)8388608)                // 2048*512 = 1,048,576
#define OFF_H    ((size_t)9437184)                // 2048*64
#define OFF_SV   ((size_t)9568256)                // 2048*64
#define OFF_Q    ((size_t)9699328)                // 2048*64
#define OFF_PM   ((size_t)9830400)                // 4*32*2048
#define OFF_PL   ((size_t)10092544)               // 4*32*2048
#define OFF_CT   ((size_t)10354688)               // 64*512 (C transposed)
#define OFF_CNT  ((size_t)10387456)               // 32 ints: [0..15]=s, [16..31]=o

// ---------------------------------------------------------------------------
// init: zero ov+h+sv (contiguous), q <- bq (h0=0 => q0=bq), C_t transpose,
// zero spike counters.
// ---------------------------------------------------------------------------
__global__ __launch_bounds__(256) void init_kernel(const float* __restrict__ bq,
                                                   const float* __restrict__ C,
                                                   float* __restrict__ ws) {
  int i = blockIdx.x * 256 + threadIdx.x;
  if (i < 327680) {                       // (1,048,576+131,072+131,072)/4 float4 zeros
    float4 z = {0.f, 0.f, 0.f, 0.f};
    ((float4*)(ws + OFF_OV))[i] = z;
    return;
  }
  i -= 327680;
  if (i < 131072) { ws[OFF_Q + i] = bq[i & 63]; return; }
  i -= 131072;
  if (i < 32768) {                        // C_t[k][c] = C[c][k]
    int k = i >> 9, c = i & 511;
    ws[OFF_CT + i] = C[c * 64 + k];
    return;
  }
  i -= 32768;
  if (i < 32) ((int*)(ws + OFF_CNT))[i] = 0;
}

// ---------------------------------------------------------------------------
// KV projection for ALL steps: kv[t][n][o] = sum_d x[b][t][s][d]*Wkv[o][d] + bkv[o]
// M=32768 rows (t*2048+n), K=512, Nc=128. Block: 64 rows x 128 cols.
// ---------------------------------------------------------------------------
__global__ __launch_bounds__(256) void kv_gemm_kernel(const float* __restrict__ x,
                                                      const float* __restrict__ Wkv,
                                                      const float* __restrict__ bkv,
                                                      float* __restrict__ ws) {
  __shared__ float smem[64 * 66 + 128 * 66];   // xs | wl  (50,688 B)
  float* xs = smem;              // [64][66]
  float* wl = smem + 64 * 66;    // [128][66]
  const int tid = threadIdx.x;
  const int mbase = blockIdx.x * 64;
  const int tc = tid & 15, tr = tid >> 4;   // rows r = tr+i*16, cols c = tc+j*16
  float acc[4][8];
#pragma unroll
  for (int i = 0; i < 4; ++i)
#pragma unroll
    for (int j = 0; j < 8; ++j) acc[i][j] = 0.f;

  for (int kt = 0; kt < 8; ++kt) {
    const int kb = kt * 64;
#pragma unroll
    for (int p = 0; p < 4; ++p) {          // stage x tile 64x64
      int e = tid + p * 256;
      int r = e >> 4, kq = e & 15;
      int row = mbase + r;
      int t_ = row >> 11, n = row & 2047;
      int b = n >> 8, s = n & 255;
      float4 v = *(const float4*)(x + (size_t)((b * 16 + t_) * 256 + s) * 512 + kb + kq * 4);
      float* d = xs + r * 66 + kq * 4;
      d[0] = v.x; d[1] = v.y; d[2] = v.z; d[3] = v.w;
    }
#pragma unroll
    for (int p = 0; p < 8; ++p) {          // stage Wkv tile 128x64
      int e = tid + p * 256;
      int o = e >> 4, kq = e & 15;
      float4 v = *(const float4*)(Wkv + (size_t)o * 512 + kb + kq * 4);
      float* d = wl + o * 66 + kq * 4;
      d[0] = v.x; d[1] = v.y; d[2] = v.z; d[3] = v.w;
    }
    __syncthreads();
#pragma unroll 4
    for (int k = 0; k < 64; ++k) {
      float a[4], bb[8];
#pragma unroll
      for (int i = 0; i < 4; ++i) a[i] = xs[(tr + i * 16) * 66 + k];
#pragma unroll
      for (int j = 0; j < 8; ++j) bb[j] = wl[(tc + j * 16) * 66 + k];
#pragma unroll
      for (int i = 0; i < 4; ++i)
#pragma unroll
        for (int j = 0; j < 8; ++j) acc[i][j] += a[i] * bb[j];
    }
    __syncthreads();
  }
  // bias + coalesced writeback through LDS
  float bias[8];
#pragma unroll
  for (int j = 0; j < 8; ++j) bias[j] = bkv[tc + j * 16];
  float* kvl = smem;   // reuse as [64][128]
#pragma unroll
  for (int i = 0; i < 4; ++i)
#pragma unroll
    for (int j = 0; j < 8; ++j)
      kvl[(tr + i * 16) * 128 + tc + j * 16] = acc[i][j] + bias[j];
  __syncthreads();
  float* kvout = ws + OFF_KV;
#pragma unroll
  for (int p = 0; p < 8; ++p) {
    int e = tid + p * 256;
    int r = e >> 5, cq = e & 31;
    const float* sp_ = kvl + r * 128 + cq * 4;
    float4 v; v.x = sp_[0]; v.y = sp_[1]; v.z = sp_[2]; v.w = sp_[3];
    *(float4*)(kvout + (size_t)(mbase + r) * 128 + cq * 4) = v;
  }
}

// ---------------------------------------------------------------------------
// attention partials (flash, key-split). blk: head(2b) | qtile(2b) | split(5b)
// 256 thr, 2 queries/thread. Writes m,l,acc16 per (head,split,query).
// ---------------------------------------------------------------------------
__device__ __forceinline__ void attp_body(int blk, int tid, int t,
                                          const float* __restrict__ kvbase,
                                          const float* __restrict__ qbuf,
                                          float* __restrict__ pm,
                                          float* __restrict__ pl,
                                          float* __restrict__ pacc,
                                          float* smem) {
  const int head = blk & 3;
  const int qt = (blk >> 2) & 3;
  const int sp = blk >> 4;                 // 0..31
  float* kl = smem;                        // [64][16]
  float* vl = smem + 1024;
  const float* kvt = kvbase + (size_t)t * NTOK * 128;
  {
    int key = tid >> 2, dq = tid & 3;
    const float* base = kvt + (size_t)(sp * 64 + key) * 128 + head * 16;
    float4 kk = ((const float4*)base)[dq];
    float4 vv = ((const float4*)(base + 64))[dq];
    ((float4*)kl)[key * 4 + dq] = kk;
    ((float4*)vl)[key * 4 + dq] = vv;
  }
  const int i0 = qt * 512 + tid;
  const int i1 = i0 + 256;
  float q0[16], q1[16];
  {
    const float4* qp0 = (const float4*)(qbuf + (size_t)i0 * 64 + head * 16);
    const float4* qp1 = (const float4*)(qbuf + (size_t)i1 * 64 + head * 16);
#pragma unroll
    for (int r = 0; r < 4; ++r) {
      float4 a = qp0[r];
      q0[4 * r] = a.x; q0[4 * r + 1] = a.y; q0[4 * r + 2] = a.z; q0[4 * r + 3] = a.w;
      float4 b = qp1[r];
      q1[4 * r] = b.x; q1[4 * r + 1] = b.y; q1[4 * r + 2] = b.z; q1[4 * r + 3] = b.w;
    }
  }
  __syncthreads();
  float m0 = -INFINITY, l0 = 0.f, m1 = -INFINITY, l1 = 0.f;
  float acc0[16], acc1[16];
#pragma unroll
  for (int d = 0; d < 16; ++d) { acc0[d] = 0.f; acc1[d] = 0.f; }

#pragma unroll
  for (int ch = 0; ch < 4; ++ch) {         // 16-key chunks
    float sc0[16], sc1[16];
#pragma unroll
    for (int j = 0; j < 16; ++j) {
      const float* kp = kl + (ch * 16 + j) * 16;
      float s0 = 0.f, s1 = 0.f;
#pragma unroll
      for (int d = 0; d < 16; ++d) { float kv_ = kp[d]; s0 += q0[d] * kv_; s1 += q1[d] * kv_; }
      sc0[j] = s0 * SCALE; sc1[j] = s1 * SCALE;
    }
    float mb0 = sc0[0], mb1 = sc1[0];
#pragma unroll
    for (int j = 1; j < 16; ++j) { mb0 = fmaxf(mb0, sc0[j]); mb1 = fmaxf(mb1, sc1[j]); }
    float mn0 = fmaxf(m0, mb0), mn1 = fmaxf(m1, mb1);
    float r0 = expf(m0 - mn0), r1 = expf(m1 - mn1);
    l0 *= r0; l1 *= r1;
#pragma unroll
    for (int d = 0; d < 16; ++d) { acc0[d] *= r0; acc1[d] *= r1; }
#pragma unroll
    for (int j = 0; j < 16; ++j) {
      float w0 = expf(sc0[j] - mn0), w1 = expf(sc1[j] - mn1);
      l0 += w0; l1 += w1; sc0[j] = w0; sc1[j] = w1;
    }
#pragma unroll
    for (int j = 0; j < 16; ++j) {
      const float* vp = vl + (ch * 16 + j) * 16;
      float w0 = sc0[j], w1 = sc1[j];
#pragma unroll
      for (int d = 0; d < 16; ++d) { float vv = vp[d]; acc0[d] += w0 * vv; acc1[d] += w1 * vv; }
    }
    m0 = mn0; m1 = mn1;
  }
  const int pbase = (head * NSPLIT + sp) * NTOK;
  pm[pbase + i0] = m0; pm[pbase + i1] = m1;
  pl[pbase + i0] = l0; pl[pbase + i1] = l1;
  float4* pa0 = (float4*)(pacc + (size_t)(pbase + i0) * 16);
  float4* pa1 = (float4*)(pacc + (size_t)(pbase + i1) * 16);
#pragma unroll
  for (int r = 0; r < 4; ++r) {
    float4 v0; v0.x = acc0[4 * r]; v0.y = acc0[4 * r + 1]; v0.z = acc0[4 * r + 2]; v0.w = acc0[4 * r + 3];
    pa0[r] = v0;
    float4 v1; v1.x = acc1[4 * r]; v1.y = acc1[4 * r + 1]; v1.z = acc1[4 * r + 2]; v1.w = acc1[4 * r + 3];
    pa1[r] = v1;
  }
}

__global__ __launch_bounds__(256) void attp_kernel(int t, float* __restrict__ ws) {
  __shared__ float smem[2048];
  attp_body(blockIdx.x, threadIdx.x, t, ws + OFF_KV, ws + OFF_Q,
            ws + OFF_PM, ws + OFF_PL, ws + OFF_PACC, smem);
}

// ---------------------------------------------------------------------------
// combine partials -> att ; st = h@A.T (ballot gather); su = st + att@Wo.T+bo;
// LIF-S (thr chain from int counts); write h2 spikes, sv, q(t+1)=h2@Wq.T+bq.
// One wave per token row; lane = DS index.
// ---------------------------------------------------------------------------
__device__ __forceinline__ void stageT(float* dst, const float* __restrict__ src, int tid) {
  // src [c][k] 64x64 -> dst[k*65 + c]
#pragma unroll
  for (int p = 0; p < 4; ++p) {
    int e = tid + p * 256;
    int c = e >> 4, kq = e & 15;
    float4 v = ((const float4*)src)[c * 16 + kq];
    dst[(kq * 4 + 0) * 65 + c] = v.x;
    dst[(kq * 4 + 1) * 65 + c] = v.y;
    dst[(kq * 4 + 2) * 65 + c] = v.z;
    dst[(kq * 4 + 3) * 65 + c] = v.w;
  }
}

__global__ __launch_bounds__(256) void combine_lifs_kernel(
    int t, const float* __restrict__ A, const float* __restrict__ Wq,
    const float* __restrict__ bq, const float* __restrict__ Wo,
    const float* __restrict__ bo, const float* __restrict__ thr_s0,
    float* __restrict__ ws) {
  __shared__ float At[64 * 65], Wqt[64 * 65], Wot[64 * 65];
  __shared__ float att_s[4][64];
  const int tid = threadIdx.x;
  stageT(At, A, tid); stageT(Wqt, Wq, tid); stageT(Wot, Wo, tid);

  const float* pm = ws + OFF_PM;
  const float* pl = ws + OFF_PL;
  const float* pacc = ws + OFF_PACC;
  float* h = ws + OFF_H;
  float* sv = ws + OFF_SV;
  float* qb = ws + OFF_Q;
  int* cnt = (int*)(ws + OFF_CNT);

  const int lane = tid & 63, w = tid >> 6;
  const int n = blockIdx.x * 4 + w;
  const int head = lane >> 4, d = lane & 15;
  const int pb = head * NSPLIT * NTOK + n;

  float mstar = -INFINITY;
  for (int s = 0; s < NSPLIT; ++s) mstar = fmaxf(mstar, pm[pb + s * NTOK]);
  float lst = 0.f, av = 0.f;
  for (int s = 0; s < NSPLIT; ++s) {
    float e = expf(pm[pb + s * NTOK] - mstar);
    lst += e * pl[pb + s * NTOK];
    av += e * pacc[(size_t)(pb + s * NTOK) * 16 + d];
  }
  float att = av / lst;
  att_s[w][lane] = att;
  float hv = h[n * 64 + lane];
  unsigned long long hm = __ballot(hv > 0.5f);
  __syncthreads();

  float st = 0.f;
  unsigned long long mm = hm;
  while (mm) { int k = __builtin_ctzll(mm); mm &= mm - 1; st += At[k * 65 + lane]; }
  float wo = 0.f;
#pragma unroll 8
  for (int k = 0; k < 64; ++k) wo += att_s[w][k] * Wot[k * 65 + lane];
  float su = st + wo + bo[lane];

  float thr = thr_s0[0];
  const float inv = 1.0f / 131072.0f;      // 2048*64 (power of 2 -> exact)
  for (int i = 0; i < t; ++i) {
    float mean = (float)cnt[i] * inv;
    thr = fmaxf(thr + 0.1f * (mean - 0.02f), 0.5f);
  }
  float svo = sv[n * 64 + lane];
  float vpot = svo * MEMDECAY + su;
  float spk = (vpot >= thr) ? 1.f : 0.f;
  h[n * 64 + lane] = spk;
  sv[n * 64 + lane] = vpot * (1.f - spk);
  unsigned long long sm = __ballot(spk > 0.5f);
  // q for next step
  float qv = 0.f;
  mm = sm;
  while (mm) { int k = __builtin_ctzll(mm); mm &= mm - 1; qv += Wqt[k * 65 + lane]; }
  qb[n * 64 + lane] = qv + bq[lane];
  if (lane == 0) atomicAdd(&cnt[t], __popcll(sm));
}

// ---------------------------------------------------------------------------
// LIF-O: out_pot = h2@C.T (ballot gather on C_t), LIF, write spikes to d_out,
// fused with attp(t+1) in blocks [512, 1024).
// ---------------------------------------------------------------------------
__global__ __launch_bounds__(256) void fused_out_attp_kernel(
    int t, const float* __restrict__ thr_o0, float* __restrict__ out,
    float* __restrict__ ws) {
  __shared__ float smem[2048];
  const int blk = blockIdx.x;
  if (blk >= 512) {
    attp_body(blk - 512, threadIdx.x, t + 1, ws + OFF_KV, ws + OFF_Q,
              ws + OFF_PM, ws + OFF_PL, ws + OFF_PACC, smem);
    return;
  }
  const int tid = threadIdx.x, lane = tid & 63, w = tid >> 6;
  const int n = blk * 4 + w;
  const float* h = ws + OFF_H;
  float* ov = ws + OFF_OV;
  const float* Ct = ws + OFF_CT;
  int* cnt = (int*)(ws + OFF_CNT);

  float hv = h[n * 64 + lane];
  unsigned long long hm = __ballot(hv > 0.5f);
  float thr = thr_o0[0];
  const float inv = 1.0f / 1048576.0f;     // 2048*512 (power of 2 -> exact)
  for (int i = 0; i < t; ++i) {
    float mean = (float)cnt[16 + i] * inv;
    thr = fmaxf(thr + 0.1f * (mean - 0.02f), 0.5f);
  }
  const int b = n >> 8, s = n & 255;
  float* outp = out + ((size_t)(b * 16 + t) * 256 + s) * 512;
  float* ovp = ov + (size_t)n * 512;
  int total = 0;
#pragma unroll
  for (int cc = 0; cc < 8; ++cc) {
    int c = cc * 64 + lane;
    float pot = 0.f;
    unsigned long long mm = hm;
    while (mm) { int k = __builtin_ctzll(mm); mm &= mm - 1; pot += Ct[k * 512 + c]; }
    float vo = ovp[c];
    float vpot = vo * MEMDECAY + pot;
    float spk = (vpot >= thr) ? 1.f : 0.f;
    outp[c] = spk;
    ovp[c] = vpot * (1.f - spk);
    unsigned long long bm = __ballot(spk > 0.5f);
    if (lane == 0) total += __popcll(bm);
  }
  if (lane == 0) atomicAdd(&cnt[16 + t], total);
}

// ---------------------------------------------------------------------------
extern "C" void kernel_launch(void* const* d_in, const int* in_sizes, int n_in,
                              void* d_out, int out_size, void* d_ws, size_t ws_size,
                              hipStream_t stream) {
  const float* x    = (const float*)d_in[0];
  const float* A    = (const float*)d_in[1];
  const float* C    = (const float*)d_in[2];
  const float* Wq   = (const float*)d_in[3];
  const float* bq   = (const float*)d_in[4];
  const float* Wkv  = (const float*)d_in[5];
  const float* bkv  = (const float*)d_in[6];
  const float* Wo   = (const float*)d_in[7];
  const float* bo   = (const float*)d_in[8];
  const float* th_s = (const float*)d_in[9];
  const float* th_o = (const float*)d_in[10];
  float* out = (float*)d_out;
  float* ws = (float*)d_ws;

  init_kernel<<<dim3(1921), dim3(256), 0, stream>>>(bq, C, ws);
  kv_gemm_kernel<<<dim3(512), dim3(256), 0, stream>>>(x, Wkv, bkv, ws);
  attp_kernel<<<dim3(512), dim3(256), 0, stream>>>(0, ws);
  for (int t = 0; t < TSTEPS; ++t) {
    combine_lifs_kernel<<<dim3(512), dim3(256), 0, stream>>>(t, A, Wq, bq, Wo, bo, th_s, ws);
    int g = (t < TSTEPS - 1) ? 1024 : 512;
    fused_out_attp_kernel<<<dim3(g), dim3(256), 0, stream>>>(t, th_o, out, ws);
  }
}

// Round 2
// 1257.854 us; speedup vs baseline: 1.3628x; 1.3628x over previous
//
#include <hip/hip_runtime.h>
#include <math.h>

// ---------------------------------------------------------------------------
// AttentionalSpikingSSMLayer  (B=8, T=16, S=256, D=512, DS=64, H=4, dh=16)
// N = B*S = 2048 flattened tokens; attention mixes the whole batch (as ref).
// All compute fp32 (no fp32 MFMA on CDNA4; spikes are Heaviside -> need fp32
// accuracy to avoid threshold flips).
// R1: LIF-O half rewritten from serialized ballot-gather (latency-bound,
//     111us/dispatch) to dense LDS-tiled GEMM + fused LIF epilogue.
// ---------------------------------------------------------------------------

#define NTOK   2048          // B*S
#define DS     64
#define DMODEL 512
#define NH     4
#define DH     16
#define TSTEPS 16
#define NSPLIT 32            // key splits for flash partials
#define KEYS_PER_SPLIT (NTOK / NSPLIT)   // 64

#define MEMDECAY ((float)0.6065306597126334)
#define SCALE    0.25f       // 1/sqrt(dh)

// workspace layout (float offsets)
#define OFF_KV   ((size_t)0)                      // 16*2048*128 = 4,194,304
#define OFF_PACC ((size_t)4194304)                // 4*32*2048*16 = 4,194,304
#define OFF_OV   ((size_t)8388608)                // 2048*512 = 1,048,576
#define OFF_H    ((size_t)9437184)                // 2048*64
#define OFF_SV   ((size_t)9568256)                // 2048*64
#define OFF_Q    ((size_t)9699328)                // 2048*64
#define OFF_PM   ((size_t)9830400)                // 4*32*2048
#define OFF_PL   ((size_t)10092544)               // 4*32*2048
#define OFF_CT   ((size_t)10354688)               // 64*512 (C transposed)
#define OFF_CNT  ((size_t)10387456)               // 32 ints: [0..15]=s, [16..31]=o

// ---------------------------------------------------------------------------
// init: zero ov+h+sv (contiguous), q <- bq (h0=0 => q0=bq), C_t transpose,
// zero spike counters.
// ---------------------------------------------------------------------------
__global__ __launch_bounds__(256) void init_kernel(const float* __restrict__ bq,
                                                   const float* __restrict__ C,
                                                   float* __restrict__ ws) {
  int i = blockIdx.x * 256 + threadIdx.x;
  if (i < 327680) {                       // (1,048,576+131,072+131,072)/4 float4 zeros
    float4 z = {0.f, 0.f, 0.f, 0.f};
    ((float4*)(ws + OFF_OV))[i] = z;
    return;
  }
  i -= 327680;
  if (i < 131072) { ws[OFF_Q + i] = bq[i & 63]; return; }
  i -= 131072;
  if (i < 32768) {                        // C_t[k][c] = C[c][k]
    int k = i >> 9, c = i & 511;
    ws[OFF_CT + i] = C[c * 64 + k];
    return;
  }
  i -= 32768;
  if (i < 32) ((int*)(ws + OFF_CNT))[i] = 0;
}

// ---------------------------------------------------------------------------
// KV projection for ALL steps: kv[t][n][o] = sum_d x[b][t][s][d]*Wkv[o][d] + bkv[o]
// M=32768 rows (t*2048+n), K=512, Nc=128. Block: 64 rows x 128 cols.
// ---------------------------------------------------------------------------
__global__ __launch_bounds__(256) void kv_gemm_kernel(const float* __restrict__ x,
                                                      const float* __restrict__ Wkv,
                                                      const float* __restrict__ bkv,
                                                      float* __restrict__ ws) {
  __shared__ float smem[64 * 66 + 128 * 66];   // xs | wl  (50,688 B)
  float* xs = smem;              // [64][66]
  float* wl = smem + 64 * 66;    // [128][66]
  const int tid = threadIdx.x;
  const int mbase = blockIdx.x * 64;
  const int tc = tid & 15, tr = tid >> 4;   // rows r = tr+i*16, cols c = tc+j*16
  float acc[4][8];
#pragma unroll
  for (int i = 0; i < 4; ++i)
#pragma unroll
    for (int j = 0; j < 8; ++j) acc[i][j] = 0.f;

  for (int kt = 0; kt < 8; ++kt) {
    const int kb = kt * 64;
#pragma unroll
    for (int p = 0; p < 4; ++p) {          // stage x tile 64x64
      int e = tid + p * 256;
      int r = e >> 4, kq = e & 15;
      int row = mbase + r;
      int t_ = row >> 11, n = row & 2047;
      int b = n >> 8, s = n & 255;
      float4 v = *(const float4*)(x + (size_t)((b * 16 + t_) * 256 + s) * 512 + kb + kq * 4);
      float* d = xs + r * 66 + kq * 4;
      d[0] = v.x; d[1] = v.y; d[2] = v.z; d[3] = v.w;
    }
#pragma unroll
    for (int p = 0; p < 8; ++p) {          // stage Wkv tile 128x64
      int e = tid + p * 256;
      int o = e >> 4, kq = e & 15;
      float4 v = *(const float4*)(Wkv + (size_t)o * 512 + kb + kq * 4);
      float* d = wl + o * 66 + kq * 4;
      d[0] = v.x; d[1] = v.y; d[2] = v.z; d[3] = v.w;
    }
    __syncthreads();
#pragma unroll 4
    for (int k = 0; k < 64; ++k) {
      float a[4], bb[8];
#pragma unroll
      for (int i = 0; i < 4; ++i) a[i] = xs[(tr + i * 16) * 66 + k];
#pragma unroll
      for (int j = 0; j < 8; ++j) bb[j] = wl[(tc + j * 16) * 66 + k];
#pragma unroll
      for (int i = 0; i < 4; ++i)
#pragma unroll
        for (int j = 0; j < 8; ++j) acc[i][j] += a[i] * bb[j];
    }
    __syncthreads();
  }
  // bias + coalesced writeback through LDS
  float bias[8];
#pragma unroll
  for (int j = 0; j < 8; ++j) bias[j] = bkv[tc + j * 16];
  float* kvl = smem;   // reuse as [64][128]
#pragma unroll
  for (int i = 0; i < 4; ++i)
#pragma unroll
    for (int j = 0; j < 8; ++j)
      kvl[(tr + i * 16) * 128 + tc + j * 16] = acc[i][j] + bias[j];
  __syncthreads();
  float* kvout = ws + OFF_KV;
#pragma unroll
  for (int p = 0; p < 8; ++p) {
    int e = tid + p * 256;
    int r = e >> 5, cq = e & 31;
    const float* sp_ = kvl + r * 128 + cq * 4;
    float4 v; v.x = sp_[0]; v.y = sp_[1]; v.z = sp_[2]; v.w = sp_[3];
    *(float4*)(kvout + (size_t)(mbase + r) * 128 + cq * 4) = v;
  }
}

// ---------------------------------------------------------------------------
// attention partials (flash, key-split). blk: head(2b) | qtile(2b) | split(5b)
// 256 thr, 2 queries/thread. Writes m,l,acc16 per (head,split,query).
// ---------------------------------------------------------------------------
__device__ __forceinline__ void attp_body(int blk, int tid, int t,
                                          const float* __restrict__ kvbase,
                                          const float* __restrict__ qbuf,
                                          float* __restrict__ pm,
                                          float* __restrict__ pl,
                                          float* __restrict__ pacc,
                                          float* smem) {
  const int head = blk & 3;
  const int qt = (blk >> 2) & 3;
  const int sp = blk >> 4;                 // 0..31
  float* kl = smem;                        // [64][16]
  float* vl = smem + 1024;
  const float* kvt = kvbase + (size_t)t * NTOK * 128;
  {
    int key = tid >> 2, dq = tid & 3;
    const float* base = kvt + (size_t)(sp * 64 + key) * 128 + head * 16;
    float4 kk = ((const float4*)base)[dq];
    float4 vv = ((const float4*)(base + 64))[dq];
    ((float4*)kl)[key * 4 + dq] = kk;
    ((float4*)vl)[key * 4 + dq] = vv;
  }
  const int i0 = qt * 512 + tid;
  const int i1 = i0 + 256;
  float q0[16], q1[16];
  {
    const float4* qp0 = (const float4*)(qbuf + (size_t)i0 * 64 + head * 16);
    const float4* qp1 = (const float4*)(qbuf + (size_t)i1 * 64 + head * 16);
#pragma unroll
    for (int r = 0; r < 4; ++r) {
      float4 a = qp0[r];
      q0[4 * r] = a.x; q0[4 * r + 1] = a.y; q0[4 * r + 2] = a.z; q0[4 * r + 3] = a.w;
      float4 b = qp1[r];
      q1[4 * r] = b.x; q1[4 * r + 1] = b.y; q1[4 * r + 2] = b.z; q1[4 * r + 3] = b.w;
    }
  }
  __syncthreads();
  float m0 = -INFINITY, l0 = 0.f, m1 = -INFINITY, l1 = 0.f;
  float acc0[16], acc1[16];
#pragma unroll
  for (int d = 0; d < 16; ++d) { acc0[d] = 0.f; acc1[d] = 0.f; }

#pragma unroll
  for (int ch = 0; ch < 4; ++ch) {         // 16-key chunks
    float sc0[16], sc1[16];
#pragma unroll
    for (int j = 0; j < 16; ++j) {
      const float* kp = kl + (ch * 16 + j) * 16;
      float s0 = 0.f, s1 = 0.f;
#pragma unroll
      for (int d = 0; d < 16; ++d) { float kv_ = kp[d]; s0 += q0[d] * kv_; s1 += q1[d] * kv_; }
      sc0[j] = s0 * SCALE; sc1[j] = s1 * SCALE;
    }
    float mb0 = sc0[0], mb1 = sc1[0];
#pragma unroll
    for (int j = 1; j < 16; ++j) { mb0 = fmaxf(mb0, sc0[j]); mb1 = fmaxf(mb1, sc1[j]); }
    float mn0 = fmaxf(m0, mb0), mn1 = fmaxf(m1, mb1);
    float r0 = expf(m0 - mn0), r1 = expf(m1 - mn1);
    l0 *= r0; l1 *= r1;
#pragma unroll
    for (int d = 0; d < 16; ++d) { acc0[d] *= r0; acc1[d] *= r1; }
#pragma unroll
    for (int j = 0; j < 16; ++j) {
      float w0 = expf(sc0[j] - mn0), w1 = expf(sc1[j] - mn1);
      l0 += w0; l1 += w1; sc0[j] = w0; sc1[j] = w1;
    }
#pragma unroll
    for (int j = 0; j < 16; ++j) {
      const float* vp = vl + (ch * 16 + j) * 16;
      float w0 = sc0[j], w1 = sc1[j];
#pragma unroll
      for (int d = 0; d < 16; ++d) { float vv = vp[d]; acc0[d] += w0 * vv; acc1[d] += w1 * vv; }
    }
    m0 = mn0; m1 = mn1;
  }
  const int pbase = (head * NSPLIT + sp) * NTOK;
  pm[pbase + i0] = m0; pm[pbase + i1] = m1;
  pl[pbase + i0] = l0; pl[pbase + i1] = l1;
  float4* pa0 = (float4*)(pacc + (size_t)(pbase + i0) * 16);
  float4* pa1 = (float4*)(pacc + (size_t)(pbase + i1) * 16);
#pragma unroll
  for (int r = 0; r < 4; ++r) {
    float4 v0; v0.x = acc0[4 * r]; v0.y = acc0[4 * r + 1]; v0.z = acc0[4 * r + 2]; v0.w = acc0[4 * r + 3];
    pa0[r] = v0;
    float4 v1; v1.x = acc1[4 * r]; v1.y = acc1[4 * r + 1]; v1.z = acc1[4 * r + 2]; v1.w = acc1[4 * r + 3];
    pa1[r] = v1;
  }
}

__global__ __launch_bounds__(256) void attp_kernel(int t, float* __restrict__ ws) {
  __shared__ float smem[2048];
  attp_body(blockIdx.x, threadIdx.x, t, ws + OFF_KV, ws + OFF_Q,
            ws + OFF_PM, ws + OFF_PL, ws + OFF_PACC, smem);
}

// ---------------------------------------------------------------------------
// combine partials -> att ; st = h@A.T (ballot gather); su = st + att@Wo.T+bo;
// LIF-S (thr chain from int counts); write h2 spikes, sv, q(t+1)=h2@Wq.T+bq.
// One wave per token row; lane = DS index.
// ---------------------------------------------------------------------------
__device__ __forceinline__ void stageT(float* dst, const float* __restrict__ src, int tid) {
  // src [c][k] 64x64 -> dst[k*65 + c]
#pragma unroll
  for (int p = 0; p < 4; ++p) {
    int e = tid + p * 256;
    int c = e >> 4, kq = e & 15;
    float4 v = ((const float4*)src)[c * 16 + kq];
    dst[(kq * 4 + 0) * 65 + c] = v.x;
    dst[(kq * 4 + 1) * 65 + c] = v.y;
    dst[(kq * 4 + 2) * 65 + c] = v.z;
    dst[(kq * 4 + 3) * 65 + c] = v.w;
  }
}

__global__ __launch_bounds__(256) void combine_lifs_kernel(
    int t, const float* __restrict__ A, const float* __restrict__ Wq,
    const float* __restrict__ bq, const float* __restrict__ Wo,
    const float* __restrict__ bo, const float* __restrict__ thr_s0,
    float* __restrict__ ws) {
  __shared__ float At[64 * 65], Wqt[64 * 65], Wot[64 * 65];
  __shared__ float att_s[4][64];
  const int tid = threadIdx.x;
  stageT(At, A, tid); stageT(Wqt, Wq, tid); stageT(Wot, Wo, tid);

  const float* pm = ws + OFF_PM;
  const float* pl = ws + OFF_PL;
  const float* pacc = ws + OFF_PACC;
  float* h = ws + OFF_H;
  float* sv = ws + OFF_SV;
  float* qb = ws + OFF_Q;
  int* cnt = (int*)(ws + OFF_CNT);

  const int lane = tid & 63, w = tid >> 6;
  const int n = blockIdx.x * 4 + w;
  const int head = lane >> 4, d = lane & 15;
  const int pb = head * NSPLIT * NTOK + n;

  float mstar = -INFINITY;
  for (int s = 0; s < NSPLIT; ++s) mstar = fmaxf(mstar, pm[pb + s * NTOK]);
  float lst = 0.f, av = 0.f;
  for (int s = 0; s < NSPLIT; ++s) {
    float e = expf(pm[pb + s * NTOK] - mstar);
    lst += e * pl[pb + s * NTOK];
    av += e * pacc[(size_t)(pb + s * NTOK) * 16 + d];
  }
  float att = av / lst;
  att_s[w][lane] = att;
  float hv = h[n * 64 + lane];
  unsigned long long hm = __ballot(hv > 0.5f);
  __syncthreads();

  float st = 0.f;
  unsigned long long mm = hm;
  while (mm) { int k = __builtin_ctzll(mm); mm &= mm - 1; st += At[k * 65 + lane]; }
  float wo = 0.f;
#pragma unroll 8
  for (int k = 0; k < 64; ++k) wo += att_s[w][k] * Wot[k * 65 + lane];
  float su = st + wo + bo[lane];

  float thr = thr_s0[0];
  const float inv = 1.0f / 131072.0f;      // 2048*64 (power of 2 -> exact)
  for (int i = 0; i < t; ++i) {
    float mean = (float)cnt[i] * inv;
    thr = fmaxf(thr + 0.1f * (mean - 0.02f), 0.5f);
  }
  float svo = sv[n * 64 + lane];
  float vpot = svo * MEMDECAY + su;
  float spk = (vpot >= thr) ? 1.f : 0.f;
  h[n * 64 + lane] = spk;
  sv[n * 64 + lane] = vpot * (1.f - spk);
  unsigned long long sm = __ballot(spk > 0.5f);
  // q for next step
  float qv = 0.f;
  mm = sm;
  while (mm) { int k = __builtin_ctzll(mm); mm &= mm - 1; qv += Wqt[k * 65 + lane]; }
  qb[n * 64 + lane] = qv + bq[lane];
  if (lane == 0) atomicAdd(&cnt[t], __popcll(sm));
}

// ---------------------------------------------------------------------------
// LIF-O as dense tiled GEMM: out_pot = h2 @ C.T via LDS tiles (h is 0/1 so
// fma order == gather order, bit-exact), fused LIF epilogue, fused with
// attp(t+1) in blocks [256, 768).
// Out blocks: 256 = 32 token-tiles x 8 channel-tiles, each 64x64 outputs.
// ---------------------------------------------------------------------------
__global__ __launch_bounds__(256) void fused_out_attp_kernel(
    int t, const float* __restrict__ thr_o0, float* __restrict__ out,
    float* __restrict__ ws) {
  __shared__ float smem[64 * 66 + 64 * 68];   // hs [64][66] | cts [64][68]
  __shared__ int scnt;
  const int blk = blockIdx.x;
  if (blk >= 256) {
    attp_body(blk - 256, threadIdx.x, t + 1, ws + OFF_KV, ws + OFF_Q,
              ws + OFF_PM, ws + OFF_PL, ws + OFF_PACC, smem);
    return;
  }
  const int tid = threadIdx.x;
  const int nt = blk >> 3;                  // token tile 0..31
  const int ct = blk & 7;                   // channel tile 0..7
  float* hs = smem;                         // [64][66]
  float* cts = smem + 64 * 66;              // [64][68]
  const float* h = ws + OFF_H;
  const float* Ct = ws + OFF_CT;
  float* ov = ws + OFF_OV;
  int* cnt = (int*)(ws + OFF_CNT);

  // stage h tile (64 tokens x 64 k) and Ct tile (64 k x 64 channels)
#pragma unroll
  for (int p = 0; p < 4; ++p) {
    int e = tid + p * 256;
    int r = e >> 4, kq = e & 15;
    float4 v = *(const float4*)(h + (size_t)(nt * 64 + r) * 64 + kq * 4);
    float* d = hs + r * 66 + kq * 4;
    d[0] = v.x; d[1] = v.y; d[2] = v.z; d[3] = v.w;
  }
#pragma unroll
  for (int p = 0; p < 4; ++p) {
    int e = tid + p * 256;
    int k = e >> 4, cq = e & 15;
    float4 v = *(const float4*)(Ct + (size_t)k * 512 + ct * 64 + cq * 4);
    float* d = cts + k * 68 + cq * 4;
    d[0] = v.x; d[1] = v.y; d[2] = v.z; d[3] = v.w;
  }
  if (tid == 0) scnt = 0;
  __syncthreads();

  const int tr = tid >> 4, tc = tid & 15;   // rows tr+i*16, cols tc*4+j
  float acc[4][4];
#pragma unroll
  for (int i = 0; i < 4; ++i)
#pragma unroll
    for (int j = 0; j < 4; ++j) acc[i][j] = 0.f;

#pragma unroll 4
  for (int k = 0; k < 64; ++k) {
    float hv[4];
#pragma unroll
    for (int i = 0; i < 4; ++i) hv[i] = hs[(tr + i * 16) * 66 + k];
    const float* cp = cts + k * 68 + tc * 4;
    float c0 = cp[0], c1 = cp[1], c2 = cp[2], c3 = cp[3];
#pragma unroll
    for (int i = 0; i < 4; ++i) {
      acc[i][0] += hv[i] * c0;
      acc[i][1] += hv[i] * c1;
      acc[i][2] += hv[i] * c2;
      acc[i][3] += hv[i] * c3;
    }
  }

  // threshold chain (bit-exact: counts are ints, divisor 2^20)
  float thr = thr_o0[0];
  const float inv = 1.0f / 1048576.0f;      // 2048*512
  for (int i = 0; i < t; ++i) {
    float mean = (float)cnt[16 + i] * inv;
    thr = fmaxf(thr + 0.1f * (mean - 0.02f), 0.5f);
  }

  int mycount = 0;
#pragma unroll
  for (int i = 0; i < 4; ++i) {
    int n = nt * 64 + tr + i * 16;
    int b = n >> 8, s = n & 255;
    size_t coff = (size_t)ct * 64 + tc * 4;
    float* ovp = ov + (size_t)n * 512 + coff;
    float* outp = out + ((size_t)(b * 16 + t) * 256 + s) * 512 + coff;
    float4 o = *(float4*)ovp;
    float v0 = o.x * MEMDECAY + acc[i][0];
    float v1 = o.y * MEMDECAY + acc[i][1];
    float v2 = o.z * MEMDECAY + acc[i][2];
    float v3 = o.w * MEMDECAY + acc[i][3];
    float s0 = (v0 >= thr) ? 1.f : 0.f;
    float s1 = (v1 >= thr) ? 1.f : 0.f;
    float s2 = (v2 >= thr) ? 1.f : 0.f;
    float s3 = (v3 >= thr) ? 1.f : 0.f;
    float4 sp; sp.x = s0; sp.y = s1; sp.z = s2; sp.w = s3;
    *(float4*)outp = sp;
    float4 nv; nv.x = v0 * (1.f - s0); nv.y = v1 * (1.f - s1);
    nv.z = v2 * (1.f - s2); nv.w = v3 * (1.f - s3);
    *(float4*)ovp = nv;
    mycount += (int)(s0 + s1 + s2 + s3);
  }
  atomicAdd(&scnt, mycount);
  __syncthreads();
  if (tid == 0) atomicAdd(&cnt[16 + t], scnt);
}

// ---------------------------------------------------------------------------
extern "C" void kernel_launch(void* const* d_in, const int* in_sizes, int n_in,
                              void* d_out, int out_size, void* d_ws, size_t ws_size,
                              hipStream_t stream) {
  const float* x    = (const float*)d_in[0];
  const float* A    = (const float*)d_in[1];
  const float* C    = (const float*)d_in[2];
  const float* Wq   = (const float*)d_in[3];
  const float* bq   = (const float*)d_in[4];
  const float* Wkv  = (const float*)d_in[5];
  const float* bkv  = (const float*)d_in[6];
  const float* Wo   = (const float*)d_in[7];
  const float* bo   = (const float*)d_in[8];
  const float* th_s = (const float*)d_in[9];
  const float* th_o = (const float*)d_in[10];
  float* out = (float*)d_out;
  float* ws = (float*)d_ws;

  init_kernel<<<dim3(1921), dim3(256), 0, stream>>>(bq, C, ws);
  kv_gemm_kernel<<<dim3(512), dim3(256), 0, stream>>>(x, Wkv, bkv, ws);
  attp_kernel<<<dim3(512), dim3(256), 0, stream>>>(0, ws);
  for (int t = 0; t < TSTEPS; ++t) {
    combine_lifs_kernel<<<dim3(512), dim3(256), 0, stream>>>(t, A, Wq, bq, Wo, bo, th_s, ws);
    int g = (t < TSTEPS - 1) ? 768 : 256;
    fused_out_attp_kernel<<<dim3(g), dim3(256), 0, stream>>>(t, th_o, out, ws);
  }
}

// Round 3
// 1001.995 us; speedup vs baseline: 1.7108x; 1.2553x over previous
//
#include <hip/hip_runtime.h>
#include <math.h>

// ---------------------------------------------------------------------------
// AttentionalSpikingSSMLayer  (B=8, T=16, S=256, D=512, DS=64, H=4, dh=16)
// All compute fp32 (no fp32 MFMA on CDNA4; Heaviside spikes need fp32 margin).
// R1: LIF-O ballot-gather -> dense LDS GEMM (1714 -> 1258 us).
// R2: kv_gemm vectorized LDS (b128 frags, pre-transposed Wkv_t) — was LDS-BW
//     bound on scalar ds_read_b32; combine_lifs gathers -> dense b128 dots;
//     atomics reduced per-block.
// ---------------------------------------------------------------------------

#define NTOK   2048          // B*S
#define TSTEPS 16
#define NSPLIT 32            // key splits for flash partials

#define MEMDECAY ((float)0.6065306597126334)
#define SCALE    0.25f       // 1/sqrt(dh)

// workspace layout (float offsets)
#define OFF_KV   ((size_t)0)                      // 16*2048*128 = 4,194,304
#define OFF_PACC ((size_t)4194304)                // 4*32*2048*16 = 4,194,304
#define OFF_OV   ((size_t)8388608)                // 2048*512 = 1,048,576
#define OFF_H    ((size_t)9437184)                // 2048*64
#define OFF_SV   ((size_t)9568256)                // 2048*64
#define OFF_Q    ((size_t)9699328)                // 2048*64
#define OFF_PM   ((size_t)9830400)                // 4*32*2048
#define OFF_PL   ((size_t)10092544)               // 4*32*2048
#define OFF_CT   ((size_t)10354688)               // 64*512 (C transposed)
#define OFF_CNT  ((size_t)10387456)               // 32 ints: [0..15]=s, [16..31]=o
#define OFF_WT   ((size_t)10387488)               // 512*128 (Wkv transposed)

// ---------------------------------------------------------------------------
// init: zero ov+h+sv, q <- bq (h0=0 => q0=bq), C_t transpose, Wkv_t transpose,
// zero spike counters.
// ---------------------------------------------------------------------------
__global__ __launch_bounds__(256) void init_kernel(const float* __restrict__ bq,
                                                   const float* __restrict__ C,
                                                   const float* __restrict__ Wkv,
                                                   float* __restrict__ ws) {
  int i = blockIdx.x * 256 + threadIdx.x;
  if (i < 327680) {                       // (1,048,576+131,072+131,072)/4 float4 zeros
    float4 z = {0.f, 0.f, 0.f, 0.f};
    ((float4*)(ws + OFF_OV))[i] = z;
    return;
  }
  i -= 327680;
  if (i < 131072) { ws[OFF_Q + i] = bq[i & 63]; return; }
  i -= 131072;
  if (i < 32768) {                        // C_t[k][c] = C[c][k]
    int k = i >> 9, c = i & 511;
    ws[OFF_CT + i] = C[c * 64 + k];
    return;
  }
  i -= 32768;
  if (i < 65536) {                        // Wkv_t[k][o] = Wkv[o][k]
    int k = i >> 7, o = i & 127;
    ws[OFF_WT + i] = Wkv[o * 512 + k];
    return;
  }
  i -= 65536;
  if (i < 32) ((int*)(ws + OFF_CNT))[i] = 0;
}

// ---------------------------------------------------------------------------
// KV projection for ALL steps: kv[t][n][o] = sum_d x[row][d]*Wkv[o][d] + bkv[o]
// M=32768 rows, K=512, Nc=128. Block: 64 rows x 128 cols, thread: 4x8.
// A tile row-major (b128 k-vectors), B tile k-major from Wkv_t (b128 col-vecs).
// ---------------------------------------------------------------------------
__global__ __launch_bounds__(256) void kv_gemm_kernel(const float* __restrict__ x,
                                                      const float* __restrict__ wkt,
                                                      const float* __restrict__ bkv,
                                                      float* __restrict__ ws) {
  __shared__ float xs[64 * 68];        // rows x k, stride 68
  __shared__ float wt[64 * 136];       // k x cols, stride 136
  const int tid = threadIdx.x;
  const int mbase = blockIdx.x * 64;
  const int rg = tid >> 4;             // rows rg*4 .. rg*4+3
  const int cg = tid & 15;             // cols cg*8 .. cg*8+7

  float acc[4][8];
#pragma unroll
  for (int i = 0; i < 4; ++i)
#pragma unroll
    for (int j = 0; j < 8; ++j) acc[i][j] = 0.f;

  for (int kt = 0; kt < 8; ++kt) {
    const int kb = kt * 64;
    // stage x tile 64 rows x 64 k (row-major, b128 stores)
#pragma unroll
    for (int p = 0; p < 4; ++p) {
      int e = tid + p * 256;
      int r = e >> 4, kq = e & 15;
      int row = mbase + r;
      int t_ = row >> 11, n = row & 2047;
      int b = n >> 8, s = n & 255;
      float4 v = *(const float4*)(x + (size_t)((b * 16 + t_) * 256 + s) * 512 + kb + kq * 4);
      *(float4*)(xs + r * 68 + kq * 4) = v;
    }
    // stage Wkv_t tile 64 k x 128 cols (k-major, coalesced, b128 stores)
#pragma unroll
    for (int p = 0; p < 8; ++p) {
      int e = tid + p * 256;
      int k = e >> 5, cq = e & 31;
      float4 v = *(const float4*)(wkt + (size_t)(kb + k) * 128 + cq * 4);
      *(float4*)(wt + k * 136 + cq * 4) = v;
    }
    __syncthreads();
#pragma unroll 2
    for (int kq = 0; kq < 16; ++kq) {
      float4 a0 = *(const float4*)(xs + (rg * 4 + 0) * 68 + kq * 4);
      float4 a1 = *(const float4*)(xs + (rg * 4 + 1) * 68 + kq * 4);
      float4 a2 = *(const float4*)(xs + (rg * 4 + 2) * 68 + kq * 4);
      float4 a3 = *(const float4*)(xs + (rg * 4 + 3) * 68 + kq * 4);
      const float* ap[4] = {(const float*)&a0, (const float*)&a1,
                            (const float*)&a2, (const float*)&a3};
#pragma unroll
      for (int kk = 0; kk < 3 + 1; ++kk) {
        const float* wp = wt + (kq * 4 + kk) * 136 + cg * 8;
        float4 b0 = *(const float4*)(wp);
        float4 b1 = *(const float4*)(wp + 4);
#pragma unroll
        for (int i = 0; i < 4; ++i) {
          float av = ap[i][kk];
          acc[i][0] += av * b0.x; acc[i][1] += av * b0.y;
          acc[i][2] += av * b0.z; acc[i][3] += av * b0.w;
          acc[i][4] += av * b1.x; acc[i][5] += av * b1.y;
          acc[i][6] += av * b1.z; acc[i][7] += av * b1.w;
        }
      }
    }
    __syncthreads();
  }
  // bias + direct coalesced writeback
  float4 bb0 = *(const float4*)(bkv + cg * 8);
  float4 bb1 = *(const float4*)(bkv + cg * 8 + 4);
  float* kvout = ws + OFF_KV;
#pragma unroll
  for (int i = 0; i < 4; ++i) {
    float* op = kvout + (size_t)(mbase + rg * 4 + i) * 128 + cg * 8;
    float4 v0; v0.x = acc[i][0] + bb0.x; v0.y = acc[i][1] + bb0.y;
    v0.z = acc[i][2] + bb0.z; v0.w = acc[i][3] + bb0.w;
    float4 v1; v1.x = acc[i][4] + bb1.x; v1.y = acc[i][5] + bb1.y;
    v1.z = acc[i][6] + bb1.z; v1.w = acc[i][7] + bb1.w;
    *(float4*)(op) = v0;
    *(float4*)(op + 4) = v1;
  }
}

// ---------------------------------------------------------------------------
// attention partials (flash, key-split). blk: head(2b) | qtile(2b) | split(5b)
// 256 thr, 2 queries/thread. Writes m,l,acc16 per (head,split,query).
// ---------------------------------------------------------------------------
__device__ __forceinline__ void attp_body(int blk, int tid, int t,
                                          const float* __restrict__ kvbase,
                                          const float* __restrict__ qbuf,
                                          float* __restrict__ pm,
                                          float* __restrict__ pl,
                                          float* __restrict__ pacc,
                                          float* smem) {
  const int head = blk & 3;
  const int qt = (blk >> 2) & 3;
  const int sp = blk >> 4;                 // 0..31
  float* kl = smem;                        // [64][16]
  float* vl = smem + 1024;
  const float* kvt = kvbase + (size_t)t * NTOK * 128;
  {
    int key = tid >> 2, dq = tid & 3;
    const float* base = kvt + (size_t)(sp * 64 + key) * 128 + head * 16;
    float4 kk = ((const float4*)base)[dq];
    float4 vv = ((const float4*)(base + 64))[dq];
    ((float4*)kl)[key * 4 + dq] = kk;
    ((float4*)vl)[key * 4 + dq] = vv;
  }
  const int i0 = qt * 512 + tid;
  const int i1 = i0 + 256;
  float q0[16], q1[16];
  {
    const float4* qp0 = (const float4*)(qbuf + (size_t)i0 * 64 + head * 16);
    const float4* qp1 = (const float4*)(qbuf + (size_t)i1 * 64 + head * 16);
#pragma unroll
    for (int r = 0; r < 4; ++r) {
      float4 a = qp0[r];
      q0[4 * r] = a.x; q0[4 * r + 1] = a.y; q0[4 * r + 2] = a.z; q0[4 * r + 3] = a.w;
      float4 b = qp1[r];
      q1[4 * r] = b.x; q1[4 * r + 1] = b.y; q1[4 * r + 2] = b.z; q1[4 * r + 3] = b.w;
    }
  }
  __syncthreads();
  float m0 = -INFINITY, l0 = 0.f, m1 = -INFINITY, l1 = 0.f;
  float acc0[16], acc1[16];
#pragma unroll
  for (int d = 0; d < 16; ++d) { acc0[d] = 0.f; acc1[d] = 0.f; }

#pragma unroll
  for (int ch = 0; ch < 4; ++ch) {         // 16-key chunks
    float sc0[16], sc1[16];
#pragma unroll
    for (int j = 0; j < 16; ++j) {
      const float* kp = kl + (ch * 16 + j) * 16;
      float s0 = 0.f, s1 = 0.f;
#pragma unroll
      for (int d = 0; d < 16; ++d) { float kv_ = kp[d]; s0 += q0[d] * kv_; s1 += q1[d] * kv_; }
      sc0[j] = s0 * SCALE; sc1[j] = s1 * SCALE;
    }
    float mb0 = sc0[0], mb1 = sc1[0];
#pragma unroll
    for (int j = 1; j < 16; ++j) { mb0 = fmaxf(mb0, sc0[j]); mb1 = fmaxf(mb1, sc1[j]); }
    float mn0 = fmaxf(m0, mb0), mn1 = fmaxf(m1, mb1);
    float r0 = expf(m0 - mn0), r1 = expf(m1 - mn1);
    l0 *= r0; l1 *= r1;
#pragma unroll
    for (int d = 0; d < 16; ++d) { acc0[d] *= r0; acc1[d] *= r1; }
#pragma unroll
    for (int j = 0; j < 16; ++j) {
      float w0 = expf(sc0[j] - mn0), w1 = expf(sc1[j] - mn1);
      l0 += w0; l1 += w1; sc0[j] = w0; sc1[j] = w1;
    }
#pragma unroll
    for (int j = 0; j < 16; ++j) {
      const float* vp = vl + (ch * 16 + j) * 16;
      float w0 = sc0[j], w1 = sc1[j];
#pragma unroll
      for (int d = 0; d < 16; ++d) { float vv = vp[d]; acc0[d] += w0 * vv; acc1[d] += w1 * vv; }
    }
    m0 = mn0; m1 = mn1;
  }
  const int pbase = (head * NSPLIT + sp) * NTOK;
  pm[pbase + i0] = m0; pm[pbase + i1] = m1;
  pl[pbase + i0] = l0; pl[pbase + i1] = l1;
  float4* pa0 = (float4*)(pacc + (size_t)(pbase + i0) * 16);
  float4* pa1 = (float4*)(pacc + (size_t)(pbase + i1) * 16);
#pragma unroll
  for (int r = 0; r < 4; ++r) {
    float4 v0; v0.x = acc0[4 * r]; v0.y = acc0[4 * r + 1]; v0.z = acc0[4 * r + 2]; v0.w = acc0[4 * r + 3];
    pa0[r] = v0;
    float4 v1; v1.x = acc1[4 * r]; v1.y = acc1[4 * r + 1]; v1.z = acc1[4 * r + 2]; v1.w = acc1[4 * r + 3];
    pa1[r] = v1;
  }
}

__global__ __launch_bounds__(256) void attp_kernel(int t, float* __restrict__ ws) {
  __shared__ float smem[2048];
  attp_body(blockIdx.x, threadIdx.x, t, ws + OFF_KV, ws + OFF_Q,
            ws + OFF_PM, ws + OFF_PL, ws + OFF_PACC, smem);
}

// ---------------------------------------------------------------------------
// combine partials -> att ; su = h@A.T + att@Wo.T + bo via dense b128 dots
// (h/spk/att broadcast from LDS; 0*w terms exact -> bit-identical to gather);
// LIF-S; h2 spikes, sv, q(t+1)=h2@Wq.T+bq. One wave per token row.
// ---------------------------------------------------------------------------
__global__ __launch_bounds__(256) void combine_lifs_kernel(
    int t, const float* __restrict__ A, const float* __restrict__ Wq,
    const float* __restrict__ bq, const float* __restrict__ Wo,
    const float* __restrict__ bo, const float* __restrict__ thr_s0,
    float* __restrict__ ws) {
  __shared__ float As[64 * 68], Wqs[64 * 68], Wos[64 * 68];  // row-major, c x k
  __shared__ float att_s[4][64], hv_s[4][64], sp_s[4][64];
  __shared__ int scnt;
  const int tid = threadIdx.x;
  // stage weights row-major (no transpose; lane reads its own row)
#pragma unroll
  for (int p = 0; p < 4; ++p) {
    int e = tid + p * 256;
    int c = e >> 4, kq = e & 15;
    *(float4*)(As + c * 68 + kq * 4)  = *(const float4*)(A + c * 64 + kq * 4);
    *(float4*)(Wqs + c * 68 + kq * 4) = *(const float4*)(Wq + c * 64 + kq * 4);
    *(float4*)(Wos + c * 68 + kq * 4) = *(const float4*)(Wo + c * 64 + kq * 4);
  }
  if (tid == 0) scnt = 0;

  const float* pm = ws + OFF_PM;
  const float* pl = ws + OFF_PL;
  const float* pacc = ws + OFF_PACC;
  float* h = ws + OFF_H;
  float* sv = ws + OFF_SV;
  float* qb = ws + OFF_Q;
  int* cnt = (int*)(ws + OFF_CNT);

  const int lane = tid & 63, w = tid >> 6;
  const int n = blockIdx.x * 4 + w;
  const int head = lane >> 4, d = lane & 15;
  const int pb = head * NSPLIT * NTOK + n;

  float mstar = -INFINITY;
  for (int s = 0; s < NSPLIT; ++s) mstar = fmaxf(mstar, pm[pb + s * NTOK]);
  float lst = 0.f, av = 0.f;
  for (int s = 0; s < NSPLIT; ++s) {
    float e = expf(pm[pb + s * NTOK] - mstar);
    lst += e * pl[pb + s * NTOK];
    av += e * pacc[(size_t)(pb + s * NTOK) * 16 + d];
  }
  att_s[w][lane] = av / lst;
  float hv = h[n * 64 + lane];
  hv_s[w][lane] = hv;
  __syncthreads();

  // dense dots: st = sum_k h[k]*A[lane][k], wo = sum_k att[k]*Wo[lane][k]
  const float* Ar = As + lane * 68;
  const float* Wor = Wos + lane * 68;
  float st = 0.f, wo = 0.f;
#pragma unroll
  for (int kq = 0; kq < 16; ++kq) {
    float4 wa = *(const float4*)(Ar + kq * 4);
    float4 wb = *(const float4*)(Wor + kq * 4);
    float4 hb = *(const float4*)(&hv_s[w][kq * 4]);   // broadcast
    float4 ab = *(const float4*)(&att_s[w][kq * 4]);  // broadcast
    st += hb.x * wa.x; st += hb.y * wa.y; st += hb.z * wa.z; st += hb.w * wa.w;
    wo += ab.x * wb.x; wo += ab.y * wb.y; wo += ab.z * wb.z; wo += ab.w * wb.w;
  }
  float su = st + wo + bo[lane];

  float thr = thr_s0[0];
  const float inv = 1.0f / 131072.0f;      // 2048*64 (power of 2 -> exact)
  for (int i = 0; i < t; ++i) {
    float mean = (float)cnt[i] * inv;
    thr = fmaxf(thr + 0.1f * (mean - 0.02f), 0.5f);
  }
  float svo = sv[n * 64 + lane];
  float vpot = svo * MEMDECAY + su;
  float spk = (vpot >= thr) ? 1.f : 0.f;
  h[n * 64 + lane] = spk;
  sv[n * 64 + lane] = vpot * (1.f - spk);
  sp_s[w][lane] = spk;                     // same-wave LDS; compiler waits lgkmcnt
  unsigned long long sm = __ballot(spk > 0.5f);

  // q for next step (dense dot with spike vector)
  const float* Wqr = Wqs + lane * 68;
  float qv = 0.f;
#pragma unroll
  for (int kq = 0; kq < 16; ++kq) {
    float4 wq = *(const float4*)(Wqr + kq * 4);
    float4 sb = *(const float4*)(&sp_s[w][kq * 4]);   // broadcast
    qv += sb.x * wq.x; qv += sb.y * wq.y; qv += sb.z * wq.z; qv += sb.w * wq.w;
  }
  qb[n * 64 + lane] = qv + bq[lane];

  if (lane == 0) atomicAdd(&scnt, __popcll(sm));
  __syncthreads();
  if (tid == 0) atomicAdd(&cnt[t], scnt);
}

// ---------------------------------------------------------------------------
// LIF-O as dense tiled GEMM: out_pot = h2 @ C.T, fused LIF epilogue, fused
// with attp(t+1) in blocks [256, 768).
// ---------------------------------------------------------------------------
__global__ __launch_bounds__(256) void fused_out_attp_kernel(
    int t, const float* __restrict__ thr_o0, float* __restrict__ out,
    float* __restrict__ ws) {
  __shared__ float smem[64 * 66 + 64 * 68];   // hs [64][66] | cts [64][68]
  __shared__ int scnt;
  const int blk = blockIdx.x;
  if (blk >= 256) {
    attp_body(blk - 256, threadIdx.x, t + 1, ws + OFF_KV, ws + OFF_Q,
              ws + OFF_PM, ws + OFF_PL, ws + OFF_PACC, smem);
    return;
  }
  const int tid = threadIdx.x;
  const int nt = blk >> 3;                  // token tile 0..31
  const int ct = blk & 7;                   // channel tile 0..7
  float* hs = smem;                         // [64][66]
  float* cts = smem + 64 * 66;              // [64][68]
  const float* h = ws + OFF_H;
  const float* Ct = ws + OFF_CT;
  float* ov = ws + OFF_OV;
  int* cnt = (int*)(ws + OFF_CNT);

#pragma unroll
  for (int p = 0; p < 4; ++p) {
    int e = tid + p * 256;
    int r = e >> 4, kq = e & 15;
    float4 v = *(const float4*)(h + (size_t)(nt * 64 + r) * 64 + kq * 4);
    float* dd = hs + r * 66 + kq * 4;
    dd[0] = v.x; dd[1] = v.y; dd[2] = v.z; dd[3] = v.w;
  }
#pragma unroll
  for (int p = 0; p < 4; ++p) {
    int e = tid + p * 256;
    int k = e >> 4, cq = e & 15;
    float4 v = *(const float4*)(Ct + (size_t)k * 512 + ct * 64 + cq * 4);
    float* dd = cts + k * 68 + cq * 4;
    dd[0] = v.x; dd[1] = v.y; dd[2] = v.z; dd[3] = v.w;
  }
  if (tid == 0) scnt = 0;
  __syncthreads();

  const int tr = tid >> 4, tc = tid & 15;   // rows tr+i*16, cols tc*4+j
  float acc[4][4];
#pragma unroll
  for (int i = 0; i < 4; ++i)
#pragma unroll
    for (int j = 0; j < 4; ++j) acc[i][j] = 0.f;

#pragma unroll 4
  for (int k = 0; k < 64; ++k) {
    float hv[4];
#pragma unroll
    for (int i = 0; i < 4; ++i) hv[i] = hs[(tr + i * 16) * 66 + k];
    const float* cp = cts + k * 68 + tc * 4;
    float c0 = cp[0], c1 = cp[1], c2 = cp[2], c3 = cp[3];
#pragma unroll
    for (int i = 0; i < 4; ++i) {
      acc[i][0] += hv[i] * c0;
      acc[i][1] += hv[i] * c1;
      acc[i][2] += hv[i] * c2;
      acc[i][3] += hv[i] * c3;
    }
  }

  float thr = thr_o0[0];
  const float inv = 1.0f / 1048576.0f;      // 2048*512
  for (int i = 0; i < t; ++i) {
    float mean = (float)cnt[16 + i] * inv;
    thr = fmaxf(thr + 0.1f * (mean - 0.02f), 0.5f);
  }

  int mycount = 0;
#pragma unroll
  for (int i = 0; i < 4; ++i) {
    int n = nt * 64 + tr + i * 16;
    int b = n >> 8, s = n & 255;
    size_t coff = (size_t)ct * 64 + tc * 4;
    float* ovp = ov + (size_t)n * 512 + coff;
    float* outp = out + ((size_t)(b * 16 + t) * 256 + s) * 512 + coff;
    float4 o = *(float4*)ovp;
    float v0 = o.x * MEMDECAY + acc[i][0];
    float v1 = o.y * MEMDECAY + acc[i][1];
    float v2 = o.z * MEMDECAY + acc[i][2];
    float v3 = o.w * MEMDECAY + acc[i][3];
    float s0 = (v0 >= thr) ? 1.f : 0.f;
    float s1 = (v1 >= thr) ? 1.f : 0.f;
    float s2 = (v2 >= thr) ? 1.f : 0.f;
    float s3 = (v3 >= thr) ? 1.f : 0.f;
    float4 sp; sp.x = s0; sp.y = s1; sp.z = s2; sp.w = s3;
    *(float4*)outp = sp;
    float4 nv; nv.x = v0 * (1.f - s0); nv.y = v1 * (1.f - s1);
    nv.z = v2 * (1.f - s2); nv.w = v3 * (1.f - s3);
    *(float4*)ovp = nv;
    mycount += (int)(s0 + s1 + s2 + s3);
  }
  atomicAdd(&scnt, mycount);
  __syncthreads();
  if (tid == 0) atomicAdd(&cnt[16 + t], scnt);
}

// ---------------------------------------------------------------------------
extern "C" void kernel_launch(void* const* d_in, const int* in_sizes, int n_in,
                              void* d_out, int out_size, void* d_ws, size_t ws_size,
                              hipStream_t stream) {
  const float* x    = (const float*)d_in[0];
  const float* A    = (const float*)d_in[1];
  const float* C    = (const float*)d_in[2];
  const float* Wq   = (const float*)d_in[3];
  const float* bq   = (const float*)d_in[4];
  const float* Wkv  = (const float*)d_in[5];
  const float* bkv  = (const float*)d_in[6];
  const float* Wo   = (const float*)d_in[7];
  const float* bo   = (const float*)d_in[8];
  const float* th_s = (const float*)d_in[9];
  const float* th_o = (const float*)d_in[10];
  float* out = (float*)d_out;
  float* ws = (float*)d_ws;

  init_kernel<<<dim3(2177), dim3(256), 0, stream>>>(bq, C, Wkv, ws);
  kv_gemm_kernel<<<dim3(512), dim3(256), 0, stream>>>(x, ws + OFF_WT, bkv, ws);
  attp_kernel<<<dim3(512), dim3(256), 0, stream>>>(0, ws);
  for (int t = 0; t < TSTEPS; ++t) {
    combine_lifs_kernel<<<dim3(512), dim3(256), 0, stream>>>(t, A, Wq, bq, Wo, bo, th_s, ws);
    int g = (t < TSTEPS - 1) ? 768 : 256;
    fused_out_attp_kernel<<<dim3(g), dim3(256), 0, stream>>>(t, th_o, out, ws);
  }
}